// Round 8
// baseline (47.857 us; speedup 1.0000x reference)
//
#include <hip/hip_runtime.h>

#define ROWS 256
#define COLS 512
#define BATCH 512
#define NC 5
#define DEG 16
#define EPG (ROWS * DEG)       /* 4096 edges per graph */
#define NPG (ROWS + COLS)      /* 768 nodes per graph  */
#define NTHREADS 1024
#define EPT (EPG / NTHREADS)   /* 4 edges per thread   */
#define EPSF 1e-7f

typedef unsigned short u16;
typedef unsigned int   u32;
typedef float v2f __attribute__((ext_vector_type(2)));

__device__ __forceinline__ float sigmoid_f(float a) {
    return 1.0f / (1.0f + __expf(-a));
}
__device__ __forceinline__ float tanh_f(float a) {
    return fmaf(2.0f, 1.0f / (1.0f + __expf(-2.0f * a)), -1.0f);
}

__global__ __launch_bounds__(NTHREADS, 8) void gnni_kernel(
    const float* __restrict__ x,
    const int*   __restrict__ eidx,
    const float* __restrict__ w1_1, const float* __restrict__ b1_1,
    const float* __restrict__ w2_1, const float* __restrict__ b2_1,
    const float* __restrict__ wih_1, const float* __restrict__ whh_1,
    const float* __restrict__ bih_1, const float* __restrict__ bhh_1,
    const float* __restrict__ w1_2, const float* __restrict__ b1_2,
    const float* __restrict__ w2_2, const float* __restrict__ b2_2,
    const float* __restrict__ wih_2, const float* __restrict__ whh_2,
    const float* __restrict__ bih_2, const float* __restrict__ bhh_2,
    float* __restrict__ out)
{
    __shared__ u32  e1[EPG];          // (src | dst<<16), sorted by dst  (phase 1)
    __shared__ u32  e2[EPG];          // (src | dst<<16), sorted by src  (phase 2)
    __shared__ float msg[EPG];        // per-edge message buffer (both phases)
    __shared__ u32  cur[COLS];        // var-bin counts / cursor
    __shared__ u32  cur2[ROWS];       // check-bin counts / cursor
    __shared__ u16  ofs_v[COLS + 1];  // CSR offsets per var node
    __shared__ u16  ofs_c[ROWS + 1];  // CSR offsets per check node
    __shared__ float hc[ROWS];
    __shared__ float hv[COLS];
    __shared__ u32  wsum[8];          // per-wave scan partials (dst scan)
    __shared__ u32  wsum2[4];         // per-wave scan partials (src scan)

    const int tid  = threadIdx.x;
    const int lane = tid & 63;
    const int wid  = tid >> 6;
    const int b    = blockIdx.x;
    const int base = b * NPG;
    const long ebase = (long)b * EPG;

    // ---- load this thread's 4 edges into registers (coalesced) ----
    u32 ep[EPT];
    #pragma unroll
    for (int i = 0; i < EPT; ++i) {
        int e = tid + i * NTHREADS;
        u32 s = (u32)(eidx[ebase + e] - base);                        // [0,256)
        u32 d = (u32)(eidx[(long)BATCH * EPG + ebase + e] - base);    // [0,512)
        ep[i] = s | (d << 16);
    }

    // ============== fused counting sorts: count both keys ==============
    if (tid < COLS) cur[tid] = 0;
    else if (tid - COLS < ROWS) cur2[tid - COLS] = 0;
    __syncthreads();
    #pragma unroll
    for (int i = 0; i < EPT; ++i) {
        atomicAdd(&cur[ep[i] >> 16], 1u);
        atomicAdd(&cur2[ep[i] & 0xffffu], 1u);
    }
    __syncthreads();

    // ---- concurrent wave-level scans: dst in waves 0..7, src in waves 8..11 ----
    u32 scv = 0, scc = 0;
    if (tid < COLS) scv = cur[tid];
    if (tid >= 512 && tid < 512 + ROWS) scc = cur2[tid - 512];
    #pragma unroll
    for (int st = 1; st < 64; st <<= 1) {
        u32 t1 = __shfl_up(scv, st);
        u32 t2 = __shfl_up(scc, st);
        if (lane >= st) { scv += t1; scc += t2; }
    }
    if (tid < COLS && lane == 63) wsum[wid] = scv;
    if (tid >= 512 && tid < 512 + ROWS && lane == 63) wsum2[wid - 8] = scc;
    __syncthreads();
    if (tid < 8) {
        u32 v = wsum[tid];
        #pragma unroll
        for (int st = 1; st < 8; st <<= 1) {
            u32 t = __shfl_up(v, st);
            if (lane >= st) v += t;
        }
        wsum[tid] = v;                 // inclusive per-wave prefix
    } else if (tid >= 64 && tid < 68) {
        u32 v = wsum2[lane];
        #pragma unroll
        for (int st = 1; st < 4; st <<= 1) {
            u32 t = __shfl_up(v, st);
            if (lane >= st) v += t;
        }
        wsum2[lane] = v;
    }
    __syncthreads();
    if (tid < COLS) {
        u32 off = wid ? wsum[wid - 1] : 0u;
        ofs_v[tid + 1] = (u16)(scv + off);
        if (tid == 0) ofs_v[0] = 0;
    }
    if (tid >= 512 && tid < 512 + ROWS) {
        int w2 = wid - 8;
        u32 off = w2 ? wsum2[w2 - 1] : 0u;
        ofs_c[tid - 512 + 1] = (u16)(scc + off);
        if (tid == 512) ofs_c[0] = 0;
    }
    __syncthreads();
    if (tid < COLS) cur[tid] = ofs_v[tid];
    if (tid >= 512 && tid < 512 + ROWS) cur2[tid - 512] = ofs_c[tid - 512];
    // ---- initial node state (done here, before the placement barrier) ----
    if (tid < ROWS) hc[tid] = x[base + tid];
    else if (tid < NPG) hv[tid - ROWS] = x[base + tid];
    __syncthreads();
    #pragma unroll
    for (int i = 0; i < EPT; ++i) {
        u32 p = ep[i];
        u32 pos = atomicAdd(&cur[p >> 16], 1u);
        e1[pos] = p;
        u32 pos2 = atomicAdd(&cur2[p & 0xffffu], 1u);
        e2[pos2] = p;
    }

    // ---- weights into registers as float2 pairs (wave-uniform -> SGPRs) ----
    v2f A1[5], C1[5], B1[5], W1[5], A2[5], C2[5], B2[5], W2[5];
    #pragma unroll
    for (int j = 0; j < 5; ++j) {
        A1[j] = (v2f){w1_1[4*j],     w1_1[4*j + 2]};
        C1[j] = (v2f){w1_1[4*j + 1], w1_1[4*j + 3]};
        B1[j] = (v2f){b1_1[2*j],     b1_1[2*j + 1]};
        W1[j] = (v2f){w2_1[2*j],     w2_1[2*j + 1]};
        A2[j] = (v2f){w1_2[4*j],     w1_2[4*j + 2]};
        C2[j] = (v2f){w1_2[4*j + 1], w1_2[4*j + 3]};
        B2[j] = (v2f){b1_2[2*j],     b1_2[2*j + 1]};
        W2[j] = (v2f){w2_2[2*j],     w2_2[2*j + 1]};
    }
    const float b2_1s = b2_1[0], b2_2s = b2_2[0];
    const v2f zero2 = (v2f){0.0f, 0.0f};
    __syncthreads();

    for (int it = 0; it < NC; ++it) {
        // ===== phase 1 pass A: edge-parallel MLP (balanced, 4 edges each) =====
        #pragma unroll
        for (int i = 0; i < EPT; ++i) {
            const int e = tid + i * NTHREADS;
            const u32 p = e1[e];
            const float xj = hc[p & 0xffffu];
            const float xi = hv[p >> 16];
            const v2f xj2 = (v2f){xj, xj}, xi2 = (v2f){xi, xi};
            v2f acc = (v2f){b2_1s, 0.0f};
            #pragma unroll
            for (int j = 0; j < 5; ++j) {
                v2f t = __builtin_elementwise_fma(C1[j], xi2, B1[j]);
                t = __builtin_elementwise_fma(A1[j], xj2, t);
                t = __builtin_elementwise_max(t, zero2);
                acc = __builtin_elementwise_fma(W1[j], t, acc);
            }
            msg[e] = acc.x + acc.y;
        }
        __syncthreads();

        // ===== phase 1 pass B: lane-pair per var node, segment-sum + GRU =====
        {
            const int v    = tid >> 1;
            const int half = tid & 1;
            const int beg = ofs_v[v], end = ofs_v[v + 1];
            const int h0  = (end - beg + 1) >> 1;
            const int lo  = half ? (beg + h0) : beg;
            const int hi  = half ? end : (beg + h0);
            float part = 0.0f;
            for (int e = lo; e < hi; ++e) part += msg[e];
            part += __shfl_xor(part, 1);
            if (half == 0) {
                const float hx = part;
                const float xg = hv[v];
                float gi0 = fmaf(wih_1[0], xg, bih_1[0]);
                float gi1 = fmaf(wih_1[1], xg, bih_1[1]);
                float gi2 = fmaf(wih_1[2], xg, bih_1[2]);
                float gh0 = fmaf(whh_1[0], hx, bhh_1[0]);
                float gh1 = fmaf(whh_1[1], hx, bhh_1[1]);
                float gh2 = fmaf(whh_1[2], hx, bhh_1[2]);
                float r = sigmoid_f(gi0 + gh0);
                float z = sigmoid_f(gi1 + gh1);
                float n = tanh_f(fmaf(r, gh2, gi2));
                hv[v] = fmaf(1.0f - z, n, z * hx);
            }
        }
        __syncthreads();

        // ===== phase 2 pass A: edge-parallel MLP (uses fresh hv) =====
        #pragma unroll
        for (int i = 0; i < EPT; ++i) {
            const int e = tid + i * NTHREADS;
            const u32 p = e2[e];
            const float xi = hc[p & 0xffffu];
            const float xj = hv[p >> 16];
            const v2f xj2 = (v2f){xj, xj}, xi2 = (v2f){xi, xi};
            v2f acc = (v2f){b2_2s, 0.0f};
            #pragma unroll
            for (int j = 0; j < 5; ++j) {
                v2f t = __builtin_elementwise_fma(C2[j], xi2, B2[j]);
                t = __builtin_elementwise_fma(A2[j], xj2, t);
                t = __builtin_elementwise_max(t, zero2);
                acc = __builtin_elementwise_fma(W2[j], t, acc);
            }
            msg[e] = acc.x + acc.y;
        }
        __syncthreads();

        // ===== phase 2 pass B: 4-lane group per check node, segment-sum + GRU =====
        {
            const int c = tid >> 2;
            const int q = tid & 3;
            const int beg = ofs_c[c], end = ofs_c[c + 1];
            const int L  = end - beg;
            const int lo = beg + ((L * q) >> 2);
            const int hi = beg + ((L * (q + 1)) >> 2);
            float part = 0.0f;
            for (int e = lo; e < hi; ++e) part += msg[e];
            part += __shfl_xor(part, 1);
            part += __shfl_xor(part, 2);
            if (q == 0) {
                const float hx = part;
                const float xg = hc[c];
                float gi0 = fmaf(wih_2[0], xg, bih_2[0]);
                float gi1 = fmaf(wih_2[1], xg, bih_2[1]);
                float gi2 = fmaf(wih_2[2], xg, bih_2[2]);
                float gh0 = fmaf(whh_2[0], hx, bhh_2[0]);
                float gh1 = fmaf(whh_2[1], hx, bhh_2[1]);
                float gh2 = fmaf(whh_2[2], hx, bhh_2[2]);
                float r = sigmoid_f(gi0 + gh0);
                float z = sigmoid_f(gi1 + gh1);
                float n = tanh_f(fmaf(r, gh2, gi2));
                hc[c] = fmaf(1.0f - z, n, z * hx);
            }
        }
        __syncthreads();
    }

    // ---- epilogue: out = clip(sigmoid(-h), eps, 1-eps) ----
    if (tid < NPG) {
        float h = (tid < ROWS) ? hc[tid] : hv[tid - ROWS];
        float sgm = 1.0f / (1.0f + __expf(h));   // sigmoid(-h)
        out[base + tid] = fminf(fmaxf(sgm, EPSF), 1.0f - EPSF);
    }
}

extern "C" void kernel_launch(void* const* d_in, const int* in_sizes, int n_in,
                              void* d_out, int out_size, void* d_ws, size_t ws_size,
                              hipStream_t stream) {
    const float* x    = (const float*)d_in[0];
    const int*   eidx = (const int*)d_in[1];
    gnni_kernel<<<BATCH, NTHREADS, 0, stream>>>(
        x, eidx,
        (const float*)d_in[2],  (const float*)d_in[3],
        (const float*)d_in[4],  (const float*)d_in[5],
        (const float*)d_in[6],  (const float*)d_in[7],
        (const float*)d_in[8],  (const float*)d_in[9],
        (const float*)d_in[10], (const float*)d_in[11],
        (const float*)d_in[12], (const float*)d_in[13],
        (const float*)d_in[14], (const float*)d_in[15],
        (const float*)d_in[16], (const float*)d_in[17],
        (float*)d_out);
}

// Round 9
// 40.647 us; speedup vs baseline: 1.1774x; 1.1774x over previous
//
#include <hip/hip_runtime.h>

#define ROWS 256
#define COLS 512
#define BATCH 512
#define NC 5
#define DEG 16
#define EPG (ROWS * DEG)       /* 4096 edges per graph */
#define NPG (ROWS + COLS)      /* 768 nodes per graph  */
#define NT 512
#define EPT (EPG / NT)         /* 8 edges per thread   */
#define EPSF 1e-7f

typedef unsigned short u16;
typedef unsigned int   u32;
typedef float v2f __attribute__((ext_vector_type(2)));

__device__ __forceinline__ float sigmoid_f(float a) {
    return 1.0f / (1.0f + __expf(-a));
}
__device__ __forceinline__ float tanh_f(float a) {
    return fmaf(2.0f, 1.0f / (1.0f + __expf(-2.0f * a)), -1.0f);
}

__global__ __launch_bounds__(NT, 4) void gnni_kernel(
    const float* __restrict__ x,
    const int*   __restrict__ eidx,
    const float* __restrict__ w1_1, const float* __restrict__ b1_1,
    const float* __restrict__ w2_1, const float* __restrict__ b2_1,
    const float* __restrict__ wih_1, const float* __restrict__ whh_1,
    const float* __restrict__ bih_1, const float* __restrict__ bhh_1,
    const float* __restrict__ w1_2, const float* __restrict__ b1_2,
    const float* __restrict__ w2_2, const float* __restrict__ b2_2,
    const float* __restrict__ wih_2, const float* __restrict__ whh_2,
    const float* __restrict__ bih_2, const float* __restrict__ bhh_2,
    float* __restrict__ out)
{
    __shared__ float msg[EPG];        // per-edge messages (both phases)
    __shared__ u32  cntd[COLS];       // dst counts -> placement cursor
    __shared__ u32  cnts[ROWS];       // src counts -> placement cursor
    __shared__ u16  ofs_v[COLS + 1];  // CSR offsets per var node
    __shared__ u16  ofs_c[ROWS + 1];  // CSR offsets per check node
    __shared__ float hc[ROWS];
    __shared__ float hv[COLS];
    __shared__ u32  wsum[8];          // per-wave scan partials (dst)
    __shared__ u32  wsum2[4];         // per-wave scan partials (src)

    const int tid  = threadIdx.x;
    const int lane = tid & 63;
    const int wid  = tid >> 6;
    const int b    = blockIdx.x;
    const int base = b * NPG;
    const long ebase = (long)b * EPG;

    // ---- vectorized edge load: thread tid owns edges [tid*8, tid*8+8) ----
    const int4 sa = *(const int4*)(eidx + ebase + tid * 8);
    const int4 sb = *(const int4*)(eidx + ebase + tid * 8 + 4);
    const int4 da = *(const int4*)(eidx + (long)BATCH * EPG + ebase + tid * 8);
    const int4 db = *(const int4*)(eidx + (long)BATCH * EPG + ebase + tid * 8 + 4);
    const int sarr[EPT] = {sa.x, sa.y, sa.z, sa.w, sb.x, sb.y, sb.z, sb.w};
    const int darr[EPT] = {da.x, da.y, da.z, da.w, db.x, db.y, db.z, db.w};
    u32 ep[EPT];
    #pragma unroll
    for (int i = 0; i < EPT; ++i)
        ep[i] = (u32)(sarr[i] - base) | ((u32)(darr[i] - base) << 16);

    // ---- count both keys ----
    if (tid < COLS) cntd[tid] = 0;
    if (tid < ROWS) cnts[tid] = 0;
    __syncthreads();
    #pragma unroll
    for (int i = 0; i < EPT; ++i) {
        atomicAdd(&cntd[ep[i] >> 16], 1u);
        atomicAdd(&cnts[ep[i] & 0xffffu], 1u);
    }
    __syncthreads();

    // ---- wave-shuffle scans ----
    u32 myd = cntd[tid];              // dst scan: all 8 waves
    u32 scv = myd;
    #pragma unroll
    for (int st = 1; st < 64; st <<= 1) {
        u32 t = __shfl_up(scv, st);
        if (lane >= st) scv += t;
    }
    if (lane == 63) wsum[wid] = scv;
    u32 mys = 0, scc = 0;
    if (tid < ROWS) {                 // src scan: waves 0..3
        mys = cnts[tid];
        scc = mys;
        #pragma unroll
        for (int st = 1; st < 64; st <<= 1) {
            u32 t = __shfl_up(scc, st);
            if (lane >= st) scc += t;
        }
        if (lane == 63) wsum2[wid] = scc;
    }
    __syncthreads();
    if (tid < 8) {
        u32 v = wsum[tid];
        #pragma unroll
        for (int st = 1; st < 8; st <<= 1) {
            u32 t = __shfl_up(v, st);
            if (tid >= st) v += t;
        }
        wsum[tid] = v;
    } else if (tid < 12) {
        u32 v = wsum2[tid - 8];
        #pragma unroll
        for (int st = 1; st < 4; st <<= 1) {
            u32 t = __shfl_up(v, st);
            if (tid - 8 >= st) v += t;
        }
        wsum2[tid - 8] = v;
    }
    __syncthreads();

    // ---- write CSR offsets, rewrite counts as exclusive cursors, init h ----
    {
        u32 inc = scv + (wid ? wsum[wid - 1] : 0u);   // global inclusive
        ofs_v[tid + 1] = (u16)inc;
        if (tid == 0) ofs_v[0] = 0;
        cntd[tid] = inc - myd;                         // exclusive cursor
    }
    if (tid < ROWS) {
        u32 inc = scc + (wid ? wsum2[wid - 1] : 0u);
        ofs_c[tid + 1] = (u16)inc;
        if (tid == 0) ofs_c[0] = 0;
        cnts[tid] = inc - mys;
        hc[tid] = x[base + tid];
    }
    float hvreg = x[base + ROWS + tid];
    hv[tid] = hvreg;
    __syncthreads();

    // ---- placement: record per-edge sorted positions in registers ----
    u32 pos1[EPT], pos2[EPT];
    #pragma unroll
    for (int i = 0; i < EPT; ++i) {
        pos1[i] = atomicAdd(&cntd[ep[i] >> 16], 1u);
        pos2[i] = atomicAdd(&cnts[ep[i] & 0xffffu], 1u);
    }
    // no barrier needed: msg/ofs/h deps are all already satisfied

    // ---- weights as float2 pairs (wave-uniform -> SGPRs) ----
    v2f A1[5], C1[5], B1[5], W1[5], A2[5], C2[5], B2[5], W2[5];
    #pragma unroll
    for (int j = 0; j < 5; ++j) {
        A1[j] = (v2f){w1_1[4*j],     w1_1[4*j + 2]};
        C1[j] = (v2f){w1_1[4*j + 1], w1_1[4*j + 3]};
        B1[j] = (v2f){b1_1[2*j],     b1_1[2*j + 1]};
        W1[j] = (v2f){w2_1[2*j],     w2_1[2*j + 1]};
        A2[j] = (v2f){w1_2[4*j],     w1_2[4*j + 2]};
        C2[j] = (v2f){w1_2[4*j + 1], w1_2[4*j + 3]};
        B2[j] = (v2f){b1_2[2*j],     b1_2[2*j + 1]};
        W2[j] = (v2f){w2_2[2*j],     w2_2[2*j + 1]};
    }
    const float b2_1s = b2_1[0], b2_2s = b2_2[0];
    const v2f zero2 = (v2f){0.0f, 0.0f};

    for (int it = 0; it < NC; ++it) {
        // ===== phase 1 pass A: balanced edge-parallel MLP, scatter to msg =====
        #pragma unroll
        for (int i = 0; i < EPT; ++i) {
            const u32 p = ep[i];
            const float xj = hc[p & 0xffffu];
            const float xi = hv[p >> 16];
            const v2f xj2 = (v2f){xj, xj}, xi2 = (v2f){xi, xi};
            v2f acc = (v2f){b2_1s, 0.0f};
            #pragma unroll
            for (int j = 0; j < 5; ++j) {
                v2f t = __builtin_elementwise_fma(C1[j], xi2, B1[j]);
                t = __builtin_elementwise_fma(A1[j], xj2, t);
                t = __builtin_elementwise_max(t, zero2);
                acc = __builtin_elementwise_fma(W1[j], t, acc);
            }
            msg[pos1[i]] = acc.x + acc.y;
        }
        __syncthreads();

        // ===== phase 1 pass B: var owner segment-sum + GRU =====
        {
            const int beg = ofs_v[tid], end = ofs_v[tid + 1];
            float hx = 0.0f;
            for (int e = beg; e < end; ++e) hx += msg[e];
            const float xg = hvreg;
            float gi0 = fmaf(wih_1[0], xg, bih_1[0]);
            float gi1 = fmaf(wih_1[1], xg, bih_1[1]);
            float gi2 = fmaf(wih_1[2], xg, bih_1[2]);
            float gh0 = fmaf(whh_1[0], hx, bhh_1[0]);
            float gh1 = fmaf(whh_1[1], hx, bhh_1[1]);
            float gh2 = fmaf(whh_1[2], hx, bhh_1[2]);
            float r = sigmoid_f(gi0 + gh0);
            float z = sigmoid_f(gi1 + gh1);
            float n = tanh_f(fmaf(r, gh2, gi2));
            hvreg = fmaf(1.0f - z, n, z * hx);
            hv[tid] = hvreg;
        }
        __syncthreads();

        // ===== phase 2 pass A: balanced edge-parallel MLP (fresh hv) =====
        #pragma unroll
        for (int i = 0; i < EPT; ++i) {
            const u32 p = ep[i];
            const float xi = hc[p & 0xffffu];
            const float xj = hv[p >> 16];
            const v2f xj2 = (v2f){xj, xj}, xi2 = (v2f){xi, xi};
            v2f acc = (v2f){b2_2s, 0.0f};
            #pragma unroll
            for (int j = 0; j < 5; ++j) {
                v2f t = __builtin_elementwise_fma(C2[j], xi2, B2[j]);
                t = __builtin_elementwise_fma(A2[j], xj2, t);
                t = __builtin_elementwise_max(t, zero2);
                acc = __builtin_elementwise_fma(W2[j], t, acc);
            }
            msg[pos2[i]] = acc.x + acc.y;
        }
        __syncthreads();

        // ===== phase 2 pass B: lane-pair per check node =====
        {
            const int c    = tid >> 1;
            const int half = tid & 1;
            const int beg = ofs_c[c], end = ofs_c[c + 1];
            const int h0  = (end - beg + 1) >> 1;
            const int lo  = half ? (beg + h0) : beg;
            const int hi  = half ? end : (beg + h0);
            float part = 0.0f;
            for (int e = lo; e < hi; ++e) part += msg[e];
            part += __shfl_xor(part, 1);
            if (half == 0) {
                const float hx = part;
                const float xg = hc[c];
                float gi0 = fmaf(wih_2[0], xg, bih_2[0]);
                float gi1 = fmaf(wih_2[1], xg, bih_2[1]);
                float gi2 = fmaf(wih_2[2], xg, bih_2[2]);
                float gh0 = fmaf(whh_2[0], hx, bhh_2[0]);
                float gh1 = fmaf(whh_2[1], hx, bhh_2[1]);
                float gh2 = fmaf(whh_2[2], hx, bhh_2[2]);
                float r = sigmoid_f(gi0 + gh0);
                float z = sigmoid_f(gi1 + gh1);
                float n = tanh_f(fmaf(r, gh2, gi2));
                hc[c] = fmaf(1.0f - z, n, z * hx);
            }
        }
        __syncthreads();
    }

    // ---- epilogue: out = clip(sigmoid(-h), eps, 1-eps) ----
    {
        float sgm = 1.0f / (1.0f + __expf(hvreg));
        out[base + ROWS + tid] = fminf(fmaxf(sgm, EPSF), 1.0f - EPSF);
    }
    if (tid < ROWS) {
        float sgm = 1.0f / (1.0f + __expf(hc[tid]));
        out[base + tid] = fminf(fmaxf(sgm, EPSF), 1.0f - EPSF);
    }
}

extern "C" void kernel_launch(void* const* d_in, const int* in_sizes, int n_in,
                              void* d_out, int out_size, void* d_ws, size_t ws_size,
                              hipStream_t stream) {
    const float* x    = (const float*)d_in[0];
    const int*   eidx = (const int*)d_in[1];
    gnni_kernel<<<BATCH, NT, 0, stream>>>(
        x, eidx,
        (const float*)d_in[2],  (const float*)d_in[3],
        (const float*)d_in[4],  (const float*)d_in[5],
        (const float*)d_in[6],  (const float*)d_in[7],
        (const float*)d_in[8],  (const float*)d_in[9],
        (const float*)d_in[10], (const float*)d_in[11],
        (const float*)d_in[12], (const float*)d_in[13],
        (const float*)d_in[14], (const float*)d_in[15],
        (const float*)d_in[16], (const float*)d_in[17],
        (float*)d_out);
}